// Round 2
// baseline (883.865 us; speedup 1.0000x reference)
//
#include <hip/hip_runtime.h>
#include <hip/hip_bf16.h>

// Problem constants (from reference)
#define HH 512
#define WW 512
#define NN 8192
#define FF 2
#define BB 8
#define MM (NN * FF)      // 16384 splats per batch
#define HW (HH * WW)      // 262144 pixels per batch image

// ---- dual-dtype input load: f32mode ? float : bf16(upper-16-of-f32) ----
__device__ __forceinline__ float ld(const void* p, int i, int f32mode) {
  if (f32mode) return ((const float*)p)[i];
  unsigned u = ((const unsigned short*)p)[i];
  return __uint_as_float(u << 16);
}

// Abramowitz & Stegun 7.1.26, |err| <= 1.5e-7 — far below the threshold.
__device__ __forceinline__ float erf_f(float x) {
  float ax = fabsf(x);
  float t = 1.0f / (1.0f + 0.3275911f * ax);
  float y = t * (0.254829592f +
           t * (-0.284496736f +
           t * (1.421413741f +
           t * (-1.453152027f +
           t * 1.061405429f))));
  y = 1.0f - y * __expf(-ax * ax);
  return copysignf(y, x);
}

// K1: detect dtype, then invert the 8 4x4 transforms (Gauss-Jordan), f32.
__global__ void k_inv(const void* __restrict__ T, float* __restrict__ invT,
                      int* __restrict__ flag) {
  int b = threadIdx.x;
  if (b >= BB) return;
  // dtype probe: under f32 data, words 0/5/10 are the diagonal of matrix 0 (≈1).
  // Under bf16 data those f32 words decode to ~0.01 (high half = off-diag elem).
  const float* Tf = (const float*)T;
  int f32mode = (fabsf(Tf[0] - 1.f) < 0.4f &&
                 fabsf(Tf[5] - 1.f) < 0.4f &&
                 fabsf(Tf[10] - 1.f) < 0.4f) ? 1 : 0;
  if (b == 0) *flag = f32mode;

  float a[4][8];
  for (int r = 0; r < 4; ++r)
    for (int c = 0; c < 4; ++c) {
      a[r][c] = ld(T, b * 16 + r * 4 + c, f32mode);
      a[r][4 + c] = (r == c) ? 1.0f : 0.0f;
    }
  for (int k = 0; k < 4; ++k) {
    int p = k; float best = fabsf(a[k][k]);
    for (int i = k + 1; i < 4; ++i) {
      float v = fabsf(a[i][k]);
      if (v > best) { best = v; p = i; }
    }
    if (p != k)
      for (int c = 0; c < 8; ++c) { float tmp = a[k][c]; a[k][c] = a[p][c]; a[p][c] = tmp; }
    float inv = 1.0f / a[k][k];
    for (int c = 0; c < 8; ++c) a[k][c] *= inv;
    for (int i = 0; i < 4; ++i) {
      if (i == k) continue;
      float f = a[i][k];
      for (int c = 0; c < 8; ++c) a[i][c] -= f * a[k][c];
    }
  }
  for (int r = 0; r < 4; ++r)
    for (int c = 0; c < 4; ++c)
      invT[b * 16 + r * 4 + c] = a[r][4 + c];
}

// K2: build per-(b,m) splat records {row, col, scale, weight}; zero the f32 image.
__global__ void k_table(const void* __restrict__ centers, const void* __restrict__ scales,
                        const void* __restrict__ weights, const float* __restrict__ invT,
                        const int* __restrict__ flag,
                        float4* __restrict__ table, float4* __restrict__ img4) {
  int idx = blockIdx.x * blockDim.x + threadIdx.x;   // [0, BB*MM)
  int stride = gridDim.x * blockDim.x;
  for (int j = idx; j < BB * HW / 4; j += stride)
    img4[j] = make_float4(0.f, 0.f, 0.f, 0.f);
  if (idx >= BB * MM) return;
  int f32mode = *flag;
  int b = idx >> 14;           // MM = 2^14
  int m = idx & (MM - 1);
  int n = m >> 1;              // FF = 2
  const float* Tb = invT + b * 16;
  float cx = ld(centers, 3 * n, f32mode);
  float cy = ld(centers, 3 * n + 1, f32mode);
  float cz = ld(centers, 3 * n + 2, f32mode);
  float p0 = Tb[0]  * cx + Tb[1]  * cy + Tb[2]  * cz + Tb[3];
  float p1 = Tb[4]  * cx + Tb[5]  * cy + Tb[6]  * cz + Tb[7];
  float p3 = Tb[12] * cx + Tb[13] * cy + Tb[14] * cz + Tb[15];
  float inv = 1.0f / p3;
  float4 rec;
  rec.x = p0 * inv;            // row coordinate (A2P = 1)
  rec.y = p1 * inv;            // col coordinate
  rec.z = ld(scales, m, f32mode);
  rec.w = ld(weights, m, f32mode);
  table[idx] = rec;
}

// K3: bilinear point-mass splat of bubble_weights (atomic f32, after image zeroed).
__global__ void k_bubble(const float4* __restrict__ table, const void* __restrict__ bwv,
                         const int* __restrict__ flag, float* __restrict__ img) {
  int idx = blockIdx.x * blockDim.x + threadIdx.x;   // [0, BB*NN)
  if (idx >= BB * NN) return;
  int f32mode = *flag;
  int b = idx >> 13;           // NN = 2^13
  int n = idx & (NN - 1);
  float4 rec = table[(b << 14) + 2 * n];   // f=0 record has this gaussian's (row,col)
  float r = rec.x, c = rec.y;
  float bw = ld(bwv, n, f32mode);
  float r0f = floorf(r), c0f = floorf(c);
  float fr = r - r0f, fc = c - c0f;
  int r0 = (int)r0f, c0 = (int)c0f;
  float* ib = img + b * HW;
  int rr0 = min(max(r0, 0), HH - 1), rr1 = min(max(r0 + 1, 0), HH - 1);
  int cc0 = min(max(c0, 0), WW - 1), cc1 = min(max(c0 + 1, 0), WW - 1);
  atomicAdd(ib + (rr0 << 9) + cc0, bw * (1.f - fr) * (1.f - fc));
  atomicAdd(ib + (rr0 << 9) + cc1, bw * (1.f - fr) * fc);
  atomicAdd(ib + (rr1 << 9) + cc0, bw * fr * (1.f - fc));
  atomicAdd(ib + (rr1 << 9) + cc1, bw * fr * fc);
}

// K4: wave-cooperative gaussian scatter. One wave per (b, m) splat.
// Window truncated at 5*s (tail < 6e-7): width <= 2*ceil(5*4.04)+1 = 42 <= 64 lanes.
__global__ void k_splat(const float4* __restrict__ table, float* __restrict__ img) {
  int gid = blockIdx.x * blockDim.x + threadIdx.x;
  int wave = gid >> 6;
  int lane = gid & 63;
  int nwaves = (gridDim.x * blockDim.x) >> 6;
  for (int i = wave; i < BB * MM; i += nwaves) {
    float4 rec = table[i];
    float row = rec.x, col = rec.y, s = rec.z, w = rec.w;
    float rs = 0.70710678118f / s;           // 1/(s*sqrt(2))
    float Rf = 5.0f * s + 0.5f;
    int rlo = max(0, (int)ceilf(row - Rf));
    int rhi = min(HH - 1, (int)floorf(row + Rf));
    int clo = max(0, (int)ceilf(col - Rf));
    int chi = min(WW - 1, (int)floorf(col + Rf));
    if (rlo > rhi || clo > chi) continue;
    int nc = chi - clo + 1;
    int nr = rhi - rlo + 1;
    // column boundary erfs, lane l holds E at x = clo+l-0.5
    float Ew = erf_f(((float)(clo + lane) - 0.5f - col) * rs);
    // per-lane column profile, weight folded in: 0.25*w*(E[l+1]-E[l])
    float pwq = (__shfl_down(Ew, 1) - Ew) * (0.25f * w);
    // row boundary erfs and per-lane row deltas
    float Eh = erf_f(((float)(rlo + lane) - 0.5f - row) * rs);
    float Dh = __shfl_down(Eh, 1) - Eh;
    float* imgb = img + ((i >> 14) << 18);   // b*HW
    for (int k = 0; k < nr; ++k) {
      float dh = __shfl(Dh, k);
      if (lane < nc)
        atomicAdd(imgb + ((rlo + k) << 9) + clo + lane, dh * pwq);
    }
  }
}

// K5: f32 -> output conversion (bf16 packed or f32 passthrough, per detected mode).
__global__ void k_final(const float4* __restrict__ img4, const int* __restrict__ flag,
                        void* __restrict__ out) {
  int idx = blockIdx.x * blockDim.x + threadIdx.x;
  int stride = gridDim.x * blockDim.x;
  int f32mode = *flag;
  if (f32mode) {
    float4* o = (float4*)out;
    for (int j = idx; j < BB * HW / 4; j += stride)
      o[j] = img4[j];
  } else {
    ushort4* o = (ushort4*)out;
    for (int j = idx; j < BB * HW / 4; j += stride) {
      float4 v = img4[j];
      __hip_bfloat16 h0 = __float2bfloat16(v.x);
      __hip_bfloat16 h1 = __float2bfloat16(v.y);
      __hip_bfloat16 h2 = __float2bfloat16(v.z);
      __hip_bfloat16 h3 = __float2bfloat16(v.w);
      ushort4 t;
      t.x = *reinterpret_cast<unsigned short*>(&h0);
      t.y = *reinterpret_cast<unsigned short*>(&h1);
      t.z = *reinterpret_cast<unsigned short*>(&h2);
      t.w = *reinterpret_cast<unsigned short*>(&h3);
      o[j] = t;
    }
  }
}

extern "C" void kernel_launch(void* const* d_in, const int* in_sizes, int n_in,
                              void* d_out, int out_size, void* d_ws, size_t ws_size,
                              hipStream_t stream) {
  const void* T       = d_in[0];   // (B,4,4)
  const void* centers = d_in[1];   // (N,3)
  const void* scales  = d_in[2];   // (N,F)
  const void* weights = d_in[3];   // (N,F)
  const void* bubble  = d_in[4];   // (N,)

  char* ws = (char*)d_ws;
  float*  img   = (float*)ws;                               // 8 MB f32 accumulator
  float4* table = (float4*)(ws + (size_t)BB * HW * 4);      // 2 MB splat records
  float*  invT  = (float*)(ws + (size_t)BB * HW * 4 + (size_t)BB * MM * 16); // 512 B
  int*    flag  = (int*)(invT + BB * 16);

  k_inv<<<1, 64, 0, stream>>>(T, invT, flag);
  k_table<<<512, 256, 0, stream>>>(centers, scales, weights, invT, flag, table, (float4*)img);
  k_bubble<<<256, 256, 0, stream>>>(table, bubble, flag, img);
  k_splat<<<1024, 256, 0, stream>>>(table, img);
  k_final<<<512, 256, 0, stream>>>((const float4*)img, flag, d_out);
}

// Round 3
// 740.049 us; speedup vs baseline: 1.1943x; 1.1943x over previous
//
#include <hip/hip_runtime.h>
#include <hip/hip_bf16.h>

// Problem constants (from reference)
#define HH 512
#define WW 512
#define NN 8192
#define FF 2
#define BB 8
#define MM (NN * FF)      // 16384 splats per batch
#define HW (HH * WW)      // 262144 pixels per batch image

// ---- dual-dtype input load: f32mode ? float : bf16 ----
__device__ __forceinline__ float ld(const void* p, int i, int f32mode) {
  if (f32mode) return ((const float*)p)[i];
  unsigned u = ((const unsigned short*)p)[i];
  return __uint_as_float(u << 16);
}

// Abramowitz & Stegun 7.1.26, |err| <= 1.5e-7.
__device__ __forceinline__ float erf_f(float x) {
  float ax = fabsf(x);
  float t = 1.0f / (1.0f + 0.3275911f * ax);
  float y = t * (0.254829592f +
           t * (-0.284496736f +
           t * (1.421413741f +
           t * (-1.453152027f +
           t * 1.061405429f))));
  y = 1.0f - y * __expf(-ax * ax);
  return copysignf(y, x);
}

// K1: detect dtype, then invert the 8 4x4 transforms (Gauss-Jordan), f32.
__global__ void k_inv(const void* __restrict__ T, float* __restrict__ invT,
                      int* __restrict__ flag) {
  int b = threadIdx.x;
  if (b >= BB) return;
  // dtype probe: under f32 data, words 0/5/10 are the diagonal of matrix 0 (≈1).
  const float* Tf = (const float*)T;
  int f32mode = (fabsf(Tf[0] - 1.f) < 0.4f &&
                 fabsf(Tf[5] - 1.f) < 0.4f &&
                 fabsf(Tf[10] - 1.f) < 0.4f) ? 1 : 0;
  if (b == 0) *flag = f32mode;

  float a[4][8];
  for (int r = 0; r < 4; ++r)
    for (int c = 0; c < 4; ++c) {
      a[r][c] = ld(T, b * 16 + r * 4 + c, f32mode);
      a[r][4 + c] = (r == c) ? 1.0f : 0.0f;
    }
  for (int k = 0; k < 4; ++k) {
    int p = k; float best = fabsf(a[k][k]);
    for (int i = k + 1; i < 4; ++i) {
      float v = fabsf(a[i][k]);
      if (v > best) { best = v; p = i; }
    }
    if (p != k)
      for (int c = 0; c < 8; ++c) { float tmp = a[k][c]; a[k][c] = a[p][c]; a[p][c] = tmp; }
    float inv = 1.0f / a[k][k];
    for (int c = 0; c < 8; ++c) a[k][c] *= inv;
    for (int i = 0; i < 4; ++i) {
      if (i == k) continue;
      float f = a[i][k];
      for (int c = 0; c < 8; ++c) a[i][c] -= f * a[k][c];
    }
  }
  for (int r = 0; r < 4; ++r)
    for (int c = 0; c < 4; ++c)
      invT[b * 16 + r * 4 + c] = a[r][4 + c];
}

// K2: build per-(b,m) splat records {row, col, scale, weight}; zero the f32 image.
__global__ void k_table(const void* __restrict__ centers, const void* __restrict__ scales,
                        const void* __restrict__ weights, const float* __restrict__ invT,
                        const int* __restrict__ flag,
                        float4* __restrict__ table, float4* __restrict__ img4) {
  int idx = blockIdx.x * blockDim.x + threadIdx.x;   // [0, BB*MM)
  int stride = gridDim.x * blockDim.x;
  for (int j = idx; j < BB * HW / 4; j += stride)
    img4[j] = make_float4(0.f, 0.f, 0.f, 0.f);
  if (idx >= BB * MM) return;
  int f32mode = *flag;
  int b = idx >> 14;           // MM = 2^14
  int m = idx & (MM - 1);
  int n = m >> 1;              // FF = 2
  const float* Tb = invT + b * 16;
  float cx = ld(centers, 3 * n, f32mode);
  float cy = ld(centers, 3 * n + 1, f32mode);
  float cz = ld(centers, 3 * n + 2, f32mode);
  float p0 = Tb[0]  * cx + Tb[1]  * cy + Tb[2]  * cz + Tb[3];
  float p1 = Tb[4]  * cx + Tb[5]  * cy + Tb[6]  * cz + Tb[7];
  float p3 = Tb[12] * cx + Tb[13] * cy + Tb[14] * cz + Tb[15];
  float inv = 1.0f / p3;
  float4 rec;
  rec.x = p0 * inv;            // row coordinate (A2P = 1)
  rec.y = p1 * inv;            // col coordinate
  rec.z = ld(scales, m, f32mode);
  rec.w = ld(weights, m, f32mode);
  table[idx] = rec;
}

// K3: wave-cooperative gaussian scatter, one wave per (b,m) splat, with the
// bilinear bubble point-mass folded into the f=0 splat's wave (lanes 0-3).
// Window truncated at 5*s (tail < 6e-7): width <= 42 <= 64 lanes.
__global__ void k_splat(const float4* __restrict__ table, const void* __restrict__ bwv,
                        const int* __restrict__ flag, float* __restrict__ img) {
  int gid = blockIdx.x * blockDim.x + threadIdx.x;
  int wave = gid >> 6;
  int lane = gid & 63;
  int nwaves = (gridDim.x * blockDim.x) >> 6;
  int f32mode = *flag;
  for (int i = wave; i < BB * MM; i += nwaves) {
    float4 rec = table[i];
    float row = rec.x, col = rec.y, s = rec.z, w = rec.w;
    float* imgb = img + ((i >> 14) << 18);   // b*HW

    // ---- bubble point-mass (f=0 records only; wave-uniform branch) ----
    if ((i & 1) == 0) {
      int n = (i & (MM - 1)) >> 1;
      float bw = ld(bwv, n, f32mode);
      float r0f = floorf(row), c0f = floorf(col);
      float fr = row - r0f, fc = col - c0f;
      int r0 = (int)r0f, c0 = (int)c0f;
      int rr0 = min(max(r0, 0), HH - 1), rr1 = min(max(r0 + 1, 0), HH - 1);
      int cc0 = min(max(c0, 0), WW - 1), cc1 = min(max(c0 + 1, 0), WW - 1);
      int rsel = (lane < 2) ? rr0 : rr1;
      int csel = (lane & 1) ? cc1 : cc0;
      float wr = (lane < 2) ? (1.f - fr) : fr;
      float wc = (lane & 1) ? fc : (1.f - fc);
      if (lane < 4)
        atomicAdd(imgb + (rsel << 9) + csel, bw * wr * wc);
    }

    // ---- separable gaussian window scatter ----
    float rs = 0.70710678118f / s;           // 1/(s*sqrt(2))
    float Rf = 5.0f * s + 0.5f;
    int rlo = max(0, (int)ceilf(row - Rf));
    int rhi = min(HH - 1, (int)floorf(row + Rf));
    int clo = max(0, (int)ceilf(col - Rf));
    int chi = min(WW - 1, (int)floorf(col + Rf));
    if (rlo > rhi || clo > chi) continue;
    int nc = chi - clo + 1;
    int nr = rhi - rlo + 1;
    // column boundary erfs, lane l holds E at x = clo+l-0.5
    float Ew = erf_f(((float)(clo + lane) - 0.5f - col) * rs);
    // per-lane column profile, weight folded in: 0.25*w*(E[l+1]-E[l])
    float pwq = (__shfl_down(Ew, 1) - Ew) * (0.25f * w);
    // row boundary erfs and per-lane row deltas
    float Eh = erf_f(((float)(rlo + lane) - 0.5f - row) * rs);
    float Dh = __shfl_down(Eh, 1) - Eh;
    for (int k = 0; k < nr; ++k) {
      float dh = __shfl(Dh, k);
      if (lane < nc)
        atomicAdd(imgb + ((rlo + k) << 9) + clo + lane, dh * pwq);
    }
  }
}

// K4: f32 -> output conversion (bf16 packed or f32 passthrough, per detected mode).
__global__ void k_final(const float4* __restrict__ img4, const int* __restrict__ flag,
                        void* __restrict__ out) {
  int idx = blockIdx.x * blockDim.x + threadIdx.x;
  int stride = gridDim.x * blockDim.x;
  int f32mode = *flag;
  if (f32mode) {
    float4* o = (float4*)out;
    for (int j = idx; j < BB * HW / 4; j += stride)
      o[j] = img4[j];
  } else {
    ushort4* o = (ushort4*)out;
    for (int j = idx; j < BB * HW / 4; j += stride) {
      float4 v = img4[j];
      __hip_bfloat16 h0 = __float2bfloat16(v.x);
      __hip_bfloat16 h1 = __float2bfloat16(v.y);
      __hip_bfloat16 h2 = __float2bfloat16(v.z);
      __hip_bfloat16 h3 = __float2bfloat16(v.w);
      ushort4 t;
      t.x = *reinterpret_cast<unsigned short*>(&h0);
      t.y = *reinterpret_cast<unsigned short*>(&h1);
      t.z = *reinterpret_cast<unsigned short*>(&h2);
      t.w = *reinterpret_cast<unsigned short*>(&h3);
      o[j] = t;
    }
  }
}

extern "C" void kernel_launch(void* const* d_in, const int* in_sizes, int n_in,
                              void* d_out, int out_size, void* d_ws, size_t ws_size,
                              hipStream_t stream) {
  const void* T       = d_in[0];   // (B,4,4)
  const void* centers = d_in[1];   // (N,3)
  const void* scales  = d_in[2];   // (N,F)
  const void* weights = d_in[3];   // (N,F)
  const void* bubble  = d_in[4];   // (N,)

  char* ws = (char*)d_ws;
  float*  img   = (float*)ws;                               // 8 MB f32 accumulator
  float4* table = (float4*)(ws + (size_t)BB * HW * 4);      // 2 MB splat records
  float*  invT  = (float*)(ws + (size_t)BB * HW * 4 + (size_t)BB * MM * 16); // 512 B
  int*    flag  = (int*)(invT + BB * 16);

  k_inv<<<1, 64, 0, stream>>>(T, invT, flag);
  k_table<<<512, 256, 0, stream>>>(centers, scales, weights, invT, flag, table, (float4*)img);
  k_splat<<<2048, 256, 0, stream>>>(table, bubble, flag, img);
  k_final<<<512, 256, 0, stream>>>((const float4*)img, flag, d_out);
}